// Round 7
// baseline (594.029 us; speedup 1.0000x reference)
//
#include <hip/hip_runtime.h>
#include <stdint.h>

// ---------------------------------------------------------------------------
// EvaLinearAttention on MI355X (gfx950).
// B=8, N=4096, C=768, H=12, D=64, npt=1. I/O fp32; GEMMs bf16 MFMA.
// R1: pass_a 16-way token split. 875 -> 666us.
// R2: XCD-chunked swizzle on GEMMs: 190->180us (FETCH 250->124MB).
// R3: BK=64 2-phase: occupancy loss, 187us (reverted).
// R4: MFMA pass_b (+), packed epilogue (-VGPR 96, reverted). Net flat.
// R5/R6: R2-gemm + MFMA pass_b composition -> 583us. QKV gemm 194us @598TF
//        = 1/3 of the 8-phase reference (m201: 1563 TF). All 2-phase tweaks
//        are measured nulls -> structural port required.
// R7 (this): both GEMMs -> 8-phase 256x256 BK=64 template (T3+T4+T5+T2):
//   512 thr / 8 waves (2Mx4N), 128KiB dbuf LDS (dynamic), 1 half-tile staged
//   per phase, counted vmcnt(6) at phases 4/8 only (never 0 mid-loop),
//   setprio(1) around each 16-MFMA quadrant, slot^(row&7) LDS swizzle
//   (R3-verified involution) on source+read, raw s_barrier + lgkmcnt(0).
// ---------------------------------------------------------------------------

typedef __attribute__((ext_vector_type(8))) short short8;
typedef __attribute__((ext_vector_type(4))) float floatx4;

#define SPLIT_A 16
#define TILES_PER_BLK (32 / SPLIT_A)

#define SBAR()  do { asm volatile("" ::: "memory"); __builtin_amdgcn_s_barrier(); asm volatile("" ::: "memory"); } while (0)
#define LGKM0() do { asm volatile("s_waitcnt lgkmcnt(0)" ::: "memory"); __builtin_amdgcn_sched_barrier(0); } while (0)
#define WAITV6() asm volatile("s_waitcnt vmcnt(6)" ::: "memory")
#define WAITV0() asm volatile("s_waitcnt vmcnt(0)" ::: "memory")

__device__ __forceinline__ float b2f(unsigned short u) {
  union { unsigned int i; float f; } v; v.i = ((unsigned int)u) << 16; return v.f;
}
__device__ __forceinline__ unsigned short f2b(float f) {
  union { float f; unsigned int i; } v; v.f = f;
  unsigned int i = v.i;
  unsigned int r = (i + 0x7FFFu + ((i >> 16) & 1u)) >> 16;  // RNE
  return (unsigned short)r;
}
__device__ __forceinline__ void unpack2(unsigned int u, float& a, float& b) {
  union { unsigned int i; float f; } x, y;
  x.i = u << 16; y.i = u & 0xFFFF0000u;
  a = x.f; b = y.f;
}

__device__ __forceinline__ void stage16(const void* g, void* l) {
#if defined(__has_builtin) && __has_builtin(__builtin_amdgcn_global_load_lds)
  __builtin_amdgcn_global_load_lds(
      (const __attribute__((address_space(1))) unsigned int*)g,
      (__attribute__((address_space(3))) unsigned int*)l, 16, 0, 0);
#else
  *(uint4*)l = *(const uint4*)g;
#endif
}

// ---------------------------------------------------------------------------
__global__ __launch_bounds__(256) void f32_to_bf16(
    const float* __restrict__ in, unsigned short* __restrict__ out, int n) {
  const int i = (blockIdx.x * 256 + threadIdx.x) * 8;
  if (i + 7 < n) {
    float4 a = *(const float4*)(in + i);
    float4 b = *(const float4*)(in + i + 4);
    unsigned short tmp[8] = {f2b(a.x), f2b(a.y), f2b(a.z), f2b(a.w),
                             f2b(b.x), f2b(b.y), f2b(b.z), f2b(b.w)};
    *(uint4*)(out + i) = *(uint4*)tmp;
  }
}

// ---------------------------------------------------------------------------
// prep: convert qkv_w and proj_w to bf16, build fused qkv bias + proj bias.
// ---------------------------------------------------------------------------
__global__ __launch_bounds__(256) void prep(
    const float* __restrict__ w, const float* __restrict__ pw,
    const float* __restrict__ qb, const float* __restrict__ vb,
    const float* __restrict__ pb,
    unsigned short* __restrict__ wbf, unsigned short* __restrict__ pwbf,
    float* __restrict__ qkvb, float* __restrict__ projb) {
  const int blk = blockIdx.x, t = threadIdx.x;
  if (blk < 1152) {
    const float* src = (blk < 864) ? w : pw;
    unsigned short* dst = (blk < 864) ? wbf : pwbf;
    const int i = ((blk < 864 ? blk : blk - 864) * 256 + t) * 8;
    float4 a = *(const float4*)(src + i);
    float4 b = *(const float4*)(src + i + 4);
    unsigned short tmp[8] = {f2b(a.x), f2b(a.y), f2b(a.z), f2b(a.w),
                             f2b(b.x), f2b(b.y), f2b(b.z), f2b(b.w)};
    *(uint4*)(dst + i) = *(uint4*)tmp;
  } else {
    const int i = (blk - 1152) * 256 + t;
    if (i < 2304) qkvb[i] = (i < 768) ? qb[i] : (i >= 1536 ? vb[i - 1536] : 0.f);
    if (i < 768) projb[i] = pb[i];
  }
}

// ---------------------------------------------------------------------------
// 8-phase 256x256 bf16 GEMM, B^T: Out[M,Nout] = A[M,K]*W[Nout,K]^T + bias.
// 512 threads = 8 waves (wr = wave>>2 in {0,1} row-half; wc = wave&3 col-q).
// Wave tile 128x64; acc[8][4] f32x4. BK=64; K-tiles NT = K/64 (even).
// LDS (dynamic 128 KiB): [buf][op][half][chunk] ; chunk=(row_in_half*8+slot),
// 16B chunks, linear dest for global_load_lds; slot swizzle s^=(row&7) applied
// on the GLOBAL SOURCE and on ds_read (both-sides involution, R3-verified).
// Schedule per iteration (2 K-tiles ta=2i in buf0, tb in buf1), 8 phases:
//  P1 read buf0 A0-3+B0-3, stage(buf1, tb, A1);        Q00
//  P2 stage(buf0, ta+2, B0);                           Q01
//  P3 read buf0 A4-7, stage(buf0, ta+2, B1);           Q10
//  P4 stage(buf0, ta+2, A0);                           Q11  vmcnt(6)
//  P5 read buf1 A0-3+B0-3, stage(buf0, ta+2, A1);      Q00
//  P6 stage(buf1, tb+2, B0);                           Q01
//  P7 read buf1 A4-7, stage(buf1, tb+2, B1);           Q10
//  P8 stage(buf1, tb+2, A0);                           Q11  vmcnt(6)
// vmcnt(6)@P4: retires tb's 8 loads (6 left = ta+2's B0,B1,A0) before P5
// reads buf1. vmcnt(6)@P8: retires ta+2's 8 (6 left = tb+2's) before next P1.
// Tail iterations: guards drop stages; waits become vmcnt(0) (once).
// ---------------------------------------------------------------------------
template <int OUT_BF16>
__global__ __launch_bounds__(512, 2) void gemm256(
    const unsigned short* __restrict__ A, const unsigned short* __restrict__ W,
    const float* __restrict__ bias, void* __restrict__ Out,
    int K, int Nout, int nbn, int NT) {
  extern __shared__ __align__(16) unsigned short lds[];  // 131072 B
  const int nwg = gridDim.x;
  const int orig = blockIdx.x;
  const int wg = (orig & 7) * (nwg >> 3) + (orig >> 3);  // bijective: nwg%8==0
  const int bm = wg / nbn, bn = wg - bm * nbn;
  const int t = threadIdx.x;
  const int lane = t & 63, wave = t >> 6;
  const int wr = wave >> 2, wc = wave & 3;
  const int mr = lane & 15, kq8 = lane >> 4;

  // staging constants: thread covers chunks {t, t+512} of each half-tile
  const int rh0 = t >> 3, sl0 = t & 7;  // row-in-half / slot of chunk t
  const size_t growA = (size_t)bm * 256;
  const size_t growB = (size_t)bn * 256;

  // op: 0 = A, 1 = W. dest ushort offset: buf*32768 + op*16384 + half*8192
  //   + chunk_in_half*8 ; chunk t -> t*8, chunk t+512 -> t*8 + 4096.
  #define STAGE_HALF(buf, op, G, grow, k0, half)                               \
    do {                                                                       \
      const int row0_ = (half)*128 + rh0;                                      \
      const int row1_ = row0_ + 64;                                            \
      const unsigned short* s0_ =                                              \
          (G) + ((grow) + row0_) * (size_t)K + (k0) + ((sl0 ^ (row0_ & 7)) * 8);\
      const unsigned short* s1_ =                                              \
          (G) + ((grow) + row1_) * (size_t)K + (k0) + ((sl0 ^ (row1_ & 7)) * 8);\
      unsigned short* d0_ = lds + (buf)*32768 + (op)*16384 + (half)*8192 + t*8;\
      stage16(s0_, d0_);                                                       \
      stage16(s1_, d0_ + 4096);                                                \
    } while (0)

  floatx4 acc[8][4] = {};
  short8 afr[4][2], bfr[4][2];

  #define RD_A(buf, i, kk)                                                     \
    (*(const short8*)&lds[(buf)*32768 + (wr*128 + (i)*16 + mr)*64 +            \
        ((((kk)*4 + kq8) ^ ((wr*128 + (i)*16 + mr) & 7)) * 8)])
  #define RD_B(buf, j, kk)                                                     \
    (*(const short8*)&lds[(buf)*32768 + 16384 + (wc*64 + (j)*16 + mr)*64 +     \
        ((((kk)*4 + kq8) ^ ((wc*64 + (j)*16 + mr) & 7)) * 8)])

  #define QUAD(ih, jh)                                                         \
    do {                                                                       \
      __builtin_amdgcn_s_setprio(1);                                           \
      _Pragma("unroll")                                                        \
      for (int i_ = 0; i_ < 4; i_++)                                           \
        _Pragma("unroll")                                                      \
        for (int jr_ = 0; jr_ < 2; jr_++)                                      \
          _Pragma("unroll")                                                    \
          for (int kk_ = 0; kk_ < 2; kk_++)                                    \
            acc[(ih)*4 + i_][(jh)*2 + jr_] =                                   \
                __builtin_amdgcn_mfma_f32_16x16x32_bf16(                       \
                    afr[i_][kk_], bfr[(jh)*2 + jr_][kk_],                      \
                    acc[(ih)*4 + i_][(jh)*2 + jr_], 0, 0, 0);                  \
      __builtin_amdgcn_s_setprio(0);                                           \
    } while (0)

  // ---- prologue: tile0 -> buf0 (4 halves); tile1 -> buf1 (B0,B1,A0) ----
  STAGE_HALF(0, 0, A, growA, 0, 0);
  STAGE_HALF(0, 0, A, growA, 0, 1);
  STAGE_HALF(0, 1, W, growB, 0, 0);
  STAGE_HALF(0, 1, W, growB, 0, 1);
  STAGE_HALF(1, 1, W, growB, 64, 0);
  STAGE_HALF(1, 1, W, growB, 64, 1);
  STAGE_HALF(1, 0, A, growA, 64, 0);
  WAITV6();   // 14 issued, <=6 left -> tile0's 8 retired
  SBAR();

  const int NI = NT >> 1;
  for (int it = 0; it < NI; ++it) {
    const int ta = 2 * it, tb = ta + 1;
    const int kA = (ta + 2) * 64, kB = (tb + 2) * 64;
    const bool gA = (ta + 2) < NT, gB = (tb + 2) < NT;
    // ---- P1: buf0 Q00 ----
#pragma unroll
    for (int i = 0; i < 4; i++) { afr[i][0] = RD_A(0, i, 0); afr[i][1] = RD_A(0, i, 1); }
#pragma unroll
    for (int j = 0; j < 4; j++) { bfr[j][0] = RD_B(0, j, 0); bfr[j][1] = RD_B(0, j, 1); }
    STAGE_HALF(1, 0, A, growA, tb * 64, 1);
    SBAR(); LGKM0();
    QUAD(0, 0);
    SBAR();
    // ---- P2: buf0 Q01 ----
    if (gA) STAGE_HALF(0, 1, W, growB, kA, 0);
    SBAR();
    QUAD(0, 1);
    SBAR();
    // ---- P3: buf0 Q10 ----
#pragma unroll
    for (int i = 0; i < 4; i++) { afr[i][0] = RD_A(0, i + 4, 0); afr[i][1] = RD_A(0, i + 4, 1); }
    if (gA) STAGE_HALF(0, 1, W, growB, kA, 1);
    SBAR(); LGKM0();
    QUAD(1, 0);
    SBAR();
    // ---- P4: buf0 Q11 ; wait tb complete ----
    if (gA) STAGE_HALF(0, 0, A, growA, kA, 0);
    SBAR();
    QUAD(1, 1);
    if (gA) WAITV6(); else WAITV0();
    SBAR();
    // ---- P5: buf1 Q00 ----
#pragma unroll
    for (int i = 0; i < 4; i++) { afr[i][0] = RD_A(1, i, 0); afr[i][1] = RD_A(1, i, 1); }
#pragma unroll
    for (int j = 0; j < 4; j++) { bfr[j][0] = RD_B(1, j, 0); bfr[j][1] = RD_B(1, j, 1); }
    if (gA) STAGE_HALF(0, 0, A, growA, kA, 1);
    SBAR(); LGKM0();
    QUAD(0, 0);
    SBAR();
    // ---- P6: buf1 Q01 ----
    if (gB) STAGE_HALF(1, 1, W, growB, kB, 0);
    SBAR();
    QUAD(0, 1);
    SBAR();
    // ---- P7: buf1 Q10 ----
#pragma unroll
    for (int i = 0; i < 4; i++) { afr[i][0] = RD_A(1, i + 4, 0); afr[i][1] = RD_A(1, i + 4, 1); }
    if (gB) STAGE_HALF(1, 1, W, growB, kB, 1);
    SBAR(); LGKM0();
    QUAD(1, 0);
    SBAR();
    // ---- P8: buf1 Q11 ; wait ta+2 complete ----
    if (gB) STAGE_HALF(1, 0, A, growA, kB, 0);
    SBAR();
    QUAD(1, 1);
    if (gB) WAITV6(); else WAITV0();
    SBAR();
  }

  // ---- epilogue (R6-verified mapping): D-row=A-row=(lane>>4)*4+r, D-col=W-row=lane&15
  const int mr4 = (lane >> 4) * 4, nc = lane & 15;
#pragma unroll
  for (int j = 0; j < 4; j++) {
    const int gc = bn * 256 + wc * 64 + j * 16 + nc;
    const float bv = bias[gc];
#pragma unroll
    for (int i = 0; i < 8; i++) {
      const int gr0 = bm * 256 + wr * 128 + i * 16 + mr4;
#pragma unroll
      for (int r = 0; r < 4; r++) {
        float v = acc[i][j][r] + bv;
        if (OUT_BF16)
          ((unsigned short*)Out)[(size_t)(gr0 + r) * Nout + gc] = f2b(v);
        else
          ((float*)Out)[(size_t)(gr0 + r) * Nout + gc] = v;
      }
    }
  }
  #undef STAGE_HALF
  #undef RD_A
  #undef RD_B
  #undef QUAD
}

// ---------------------------------------------------------------------------
// pass_a (split fp32): one block per (bh, split); 2 tiles of 128 tokens.
// ---------------------------------------------------------------------------
__global__ __launch_bounds__(256) void pass_a(
    const unsigned short* __restrict__ qkv, const float* __restrict__ rope,
    float* __restrict__ kvP) {
  __shared__ float sphi[128 * 65];
  __shared__ __align__(16) unsigned short sv[128 * 64];
  const int bh = blockIdx.x, b = bh / 12, h = bh % 12;
  const int sp = blockIdx.y;
  const int t = threadIdx.x;
  const int lane = t & 63, wave = t >> 6;
  const int dg = lane >> 2;
  const int eg = lane & 3;
  float acc[4][16] = {};
  float ks4[4] = {};

  const int tile0 = sp * TILES_PER_BLK;
  for (int tile = tile0; tile < tile0 + TILES_PER_BLK; tile++) {
    __syncthreads();
    if (t < 128) {
      const int n = tile * 128 + t;
      const size_t rowb = (size_t)(b * 4096 + n) * 2304;
      const unsigned short* kp = qkv + rowb + 768 + h * 64;
      float kk[64];
#pragma unroll
      for (int c = 0; c < 8; c++) {
        uint4 u = *(const uint4*)(kp + c * 8);
        unpack2(u.x, kk[c * 8 + 0], kk[c * 8 + 1]);
        unpack2(u.y, kk[c * 8 + 2], kk[c * 8 + 3]);
        unpack2(u.z, kk[c * 8 + 4], kk[c * 8 + 5]);
        unpack2(u.w, kk[c * 8 + 6], kk[c * 8 + 7]);
      }
      if (n > 0) {
        const float* rp = rope + (size_t)(n - 1) * 128;
#pragma unroll
        for (int c = 0; c < 8; c++) {
          float sn[8], cs[8];
          *(float4*)&sn[0] = *(const float4*)(rp + c * 8);
          *(float4*)&sn[4] = *(const float4*)(rp + c * 8 + 4);
          *(float4*)&cs[0] = *(const float4*)(rp + 64 + c * 8);
          *(float4*)&cs[4] = *(const float4*)(rp + 64 + c * 8 + 4);
#pragma unroll
          for (int i = 0; i < 4; i++) {
            float e = kk[c * 8 + 2 * i], o = kk[c * 8 + 2 * i + 1];
            kk[c * 8 + 2 * i] = e * cs[2 * i] - o * sn[2 * i];
            kk[c * 8 + 2 * i + 1] = o * cs[2 * i + 1] + e * sn[2 * i + 1];
          }
        }
      }
      float mx = kk[0];
#pragma unroll
      for (int i = 1; i < 64; i++) mx = fmaxf(mx, kk[i]);
      float s = 0.f;
#pragma unroll
      for (int i = 0; i < 64; i++) { float e = __expf(kk[i] - mx); kk[i] = e; s += e; }
      const float inv = 1.f / s;
#pragma unroll
      for (int d = 0; d < 64; d++) sphi[t * 65 + d] = kk[d] * inv;
      const unsigned short* vp = qkv + rowb + 1536 + h * 64;
#pragma unroll
      for (int c = 0; c < 8; c++)
        *(uint4*)&sv[t * 64 + c * 8] = *(const uint4*)(vp + c * 8);
    }
    __syncthreads();
    const int n0 = wave * 32;
    for (int nn = n0; nn < n0 + 32; nn++) {
      float p[4];
#pragma unroll
      for (int i = 0; i < 4; i++) p[i] = sphi[nn * 65 + dg * 4 + i];
#pragma unroll
      for (int i = 0; i < 4; i++) ks4[i] += p[i];
      float vv[16];
      {
        uint4 u0 = *(const uint4*)&sv[nn * 64 + eg * 16];
        uint4 u1 = *(const uint4*)&sv[nn * 64 + eg * 16 + 8];
        unpack2(u0.x, vv[0], vv[1]);   unpack2(u0.y, vv[2], vv[3]);
        unpack2(u0.z, vv[4], vv[5]);   unpack2(u0.w, vv[6], vv[7]);
        unpack2(u1.x, vv[8], vv[9]);   unpack2(u1.y, vv[10], vv[11]);
        unpack2(u1.z, vv[12], vv[13]); unpack2(u1.w, vv[14], vv[15]);
      }
#pragma unroll
      for (int i = 0; i < 4; i++)
#pragma unroll
        for (int j = 0; j < 16; j++)
          acc[i][j] += p[i] * vv[j];
    }
  }

  __syncthreads();
  float* sred = sphi;
  float* o = kvP + ((size_t)bh * SPLIT_A + sp) * 4160;
#pragma unroll
  for (int half = 0; half < 2; half++) {
    if (wave != 0) {
      float* row = &sred[((wave - 1) * 64 + lane) * 33];
#pragma unroll
      for (int i = 0; i < 4; i++)
#pragma unroll
        for (int jj = 0; jj < 8; jj++) row[i * 8 + jj] = acc[i][half * 8 + jj];
    }
    __syncthreads();
    if (wave == 0) {
#pragma unroll
      for (int jj = 0; jj < 8; jj++) {
        float4 s4;
        float sv4[4];
#pragma unroll
        for (int i = 0; i < 4; i++) {
          float s = acc[i][half * 8 + jj];
#pragma unroll
          for (int w = 0; w < 3; w++) s += sred[(w * 64 + lane) * 33 + i * 8 + jj];
          sv4[i] = s;
        }
        s4.x = sv4[0]; s4.y = sv4[1]; s4.z = sv4[2]; s4.w = sv4[3];
        const int e = eg * 16 + half * 8 + jj;
        *(float4*)&o[e * 64 + dg * 4] = s4;
      }
    }
    __syncthreads();
  }
  if (wave != 0) {
#pragma unroll
    for (int i = 0; i < 4; i++) sred[((wave - 1) * 64 + lane) * 5 + i] = ks4[i];
  }
  __syncthreads();
  if (wave == 0 && eg == 0) {
    float4 s4;
    float sv4[4];
#pragma unroll
    for (int i = 0; i < 4; i++) {
      float s = ks4[i];
#pragma unroll
      for (int w = 0; w < 3; w++) s += sred[(w * 64 + lane) * 5 + i];
      sv4[i] = s;
    }
    s4.x = sv4[0]; s4.y = sv4[1]; s4.z = sv4[2]; s4.w = sv4[3];
    *(float4*)&o[4096 + dg * 4] = s4;
  }
}

// ---------------------------------------------------------------------------
__global__ __launch_bounds__(256) void reduce_kv(
    const float* __restrict__ kvP, float* __restrict__ kvG) {
  const int i = blockIdx.x * 256 + threadIdx.x;
  if (i >= 96 * 4160) return;
  const int bh = i / 4160, r = i - bh * 4160;
  const float* p = kvP + (size_t)bh * SPLIT_A * 4160 + r;
  float s = 0.f;
#pragma unroll
  for (int sp = 0; sp < SPLIT_A; sp++) s += p[(size_t)sp * 4160];
  kvG[i] = s;
}

// ---------------------------------------------------------------------------
// pass_b (MFMA): see R4/R6 notes. phi/kv bf16 in swizzled LDS; 32 MFMA/wave.
// ---------------------------------------------------------------------------
__global__ __launch_bounds__(256) void pass_b(
    const unsigned short* __restrict__ qkv, const float* __restrict__ rope,
    const float* __restrict__ kvG, unsigned short* __restrict__ attn) {
  __shared__ __align__(16) unsigned short sp_[256 * 64];
  __shared__ __align__(16) unsigned short skv[64 * 64];
  __shared__ float szi[256];
  __shared__ float sks[64];
  const int bh = blockIdx.x, b = bh / 12, h = bh % 12;
  const int t = threadIdx.x;
  const float* kvb = kvG + (size_t)bh * 4160;

  {
    const int e = t >> 2, q = t & 3;
    const float* src = kvb + e * 64 + q * 16;
    unsigned short tmp[16];
#pragma unroll
    for (int i = 0; i < 16; i++) tmp[i] = f2b(src[i]);
    *(uint4*)&skv[e * 64 + (((q * 2) ^ (e & 7)) * 8)] = *(uint4*)&tmp[0];
    *(uint4*)&skv[e * 64 + (((q * 2 + 1) ^ (e & 7)) * 8)] = *(uint4*)&tmp[8];
  }
  if (t < 64) sks[t] = kvb[4096 + t];
  __syncthreads();

  const int n = blockIdx.y * 256 + t;
  const size_t rowb = (size_t)(b * 4096 + n) * 2304;
  const unsigned short* qp = qkv + rowb + h * 64;
  float ph[64];
#pragma unroll
  for (int c = 0; c < 8; c++) {
    uint4 u = *(const uint4*)(qp + c * 8);
    unpack2(u.x, ph[c * 8 + 0], ph[c * 8 + 1]);
    unpack2(u.y, ph[c * 8 + 2], ph[c * 8 + 3]);
    unpack2(u.z, ph[c * 8 + 4], ph[c * 8 + 5]);
    unpack2(u.w, ph[c * 8 + 6], ph[c * 8 + 7]);
  }
  if (n > 0) {
    const float* rp = rope + (size_t)(n - 1) * 128;
#pragma unroll
    for (int c = 0; c < 8; c++) {
      float sn[8], cs[8];
      *(float4*)&sn[0] = *(const float4*)(rp + c * 8);
      *(float4*)&sn[4] = *(const float4*)(rp + c * 8 + 4);
      *(float4*)&cs[0] = *(const float4*)(rp + 64 + c * 8);
      *(float4*)&cs[4] = *(const float4*)(rp + 64 + c * 8 + 4);
#pragma unroll
      for (int i = 0; i < 4; i++) {
        float e = ph[c * 8 + 2 * i], o = ph[c * 8 + 2 * i + 1];
        ph[c * 8 + 2 * i] = e * cs[2 * i] - o * sn[2 * i];
        ph[c * 8 + 2 * i + 1] = o * cs[2 * i + 1] + e * sn[2 * i + 1];
      }
    }
  }
  float mx = ph[0];
#pragma unroll
  for (int i = 1; i < 64; i++) mx = fmaxf(mx, ph[i]);
  float s = 0.f;
#pragma unroll
  for (int i = 0; i < 64; i++) { float e = __expf(ph[i] - mx); ph[i] = e; s += e; }
  const float inv = 1.f / s;
  float z = 0.f;
#pragma unroll
  for (int i = 0; i < 64; i++) { ph[i] *= inv; z += ph[i] * sks[i]; }
  szi[t] = 1.f / (z + 1e-5f);

#pragma unroll
  for (int sl = 0; sl < 8; sl += 2) {
    unsigned short tmp[16];
#pragma unroll
    for (int i = 0; i < 16; i++) tmp[i] = f2b(ph[sl * 8 + i]);
    *(uint4*)&sp_[t * 64 + ((sl ^ (t & 7)) * 8)] = *(uint4*)&tmp[0];
    *(uint4*)&sp_[t * 64 + (((sl + 1) ^ (t & 7)) * 8)] = *(uint4*)&tmp[8];
  }
  __syncthreads();

  const int lane = t & 63, wv = t >> 6;
  const int fr = lane & 15, fq = lane >> 4;
  floatx4 acc[4][4] = {};
#pragma unroll
  for (int kk = 0; kk < 2; kk++) {
    short8 kvf[4], pf[4];
#pragma unroll
    for (int j = 0; j < 4; j++) {
      const int e = j * 16 + fr;
      kvf[j] = *(const short8*)&skv[e * 64 + (((kk * 4 + fq) ^ (e & 7)) * 8)];
    }
#pragma unroll
    for (int i = 0; i < 4; i++) {
      const int tok = wv * 64 + i * 16 + fr;
      pf[i] = *(const short8*)&sp_[tok * 64 + (((kk * 4 + fq) ^ (tok & 7)) * 8)];
    }
#pragma unroll
    for (int i = 0; i < 4; i++)
#pragma unroll
      for (int j = 0; j < 4; j++)
        acc[i][j] = __builtin_amdgcn_mfma_f32_16x16x32_bf16(kvf[j], pf[i], acc[i][j], 0, 0, 0);
  }

#pragma unroll
  for (int i = 0; i < 4; i++) {
    const int tokl = wv * 64 + i * 16 + fr;
    const float zi = szi[tokl];
    unsigned short* orow =
        attn + (size_t)(b * 4096 + blockIdx.y * 256 + tokl) * 768 + h * 64;
#pragma unroll
    for (int j = 0; j < 4; j++) {
      const int e0 = j * 16 + fq * 4;
      unsigned short pk[4] = {f2b(acc[i][j][0] * zi), f2b(acc[i][j][1] * zi),
                              f2b(acc[i][j][2] * zi), f2b(acc[i][j][3] * zi)};
      *(uint2*)(orow + e0) = *(const uint2*)pk;
    }
  }
}

// ---------------------------------------------------------------------------
__global__ __launch_bounds__(256) void ln_kernel(
    unsigned short* __restrict__ buf, const float* __restrict__ g,
    const float* __restrict__ be) {
  const int row = blockIdx.x;
  const int t = threadIdx.x;
  unsigned short* p = buf + (size_t)row * 768;
  const float x0 = b2f(p[t]), x1 = b2f(p[t + 256]), x2 = b2f(p[t + 512]);
  float s = x0 + x1 + x2;
  float ss = x0 * x0 + x1 * x1 + x2 * x2;
#pragma unroll
  for (int m = 1; m < 64; m <<= 1) { s += __shfl_xor(s, m); ss += __shfl_xor(ss, m); }
  __shared__ float red[8];
  const int wave = t >> 6, lane = t & 63;
  if (lane == 0) { red[wave] = s; red[4 + wave] = ss; }
  __syncthreads();
  s = red[0] + red[1] + red[2] + red[3];
  ss = red[4] + red[5] + red[6] + red[7];
  const float mean = s * (1.f / 768.f);
  const float var = ss * (1.f / 768.f) - mean * mean;
  const float rsq = rsqrtf(var + 1e-5f);
  p[t] = f2b((x0 - mean) * rsq * g[t] + be[t]);
  p[t + 256] = f2b((x1 - mean) * rsq * g[t + 256] + be[t + 256]);
  p[t + 512] = f2b((x2 - mean) * rsq * g[t + 512] + be[t + 512]);
}

// ---------------------------------------------------------------------------
extern "C" void kernel_launch(void* const* d_in, const int* in_sizes, int n_in,
                              void* d_out, int out_size, void* d_ws, size_t ws_size,
                              hipStream_t stream) {
  (void)in_sizes; (void)n_in; (void)out_size; (void)ws_size;
  const float* x      = (const float*)d_in[0];
  const float* rope   = (const float*)d_in[1];
  const float* qkv_w  = (const float*)d_in[2];
  const float* q_bias = (const float*)d_in[3];
  const float* v_bias = (const float*)d_in[4];
  const float* norm_g = (const float*)d_in[5];
  const float* norm_b = (const float*)d_in[6];
  const float* proj_w = (const float*)d_in[7];
  const float* proj_b = (const float*)d_in[8];

  char* ws = (char*)d_ws;
  unsigned short* qkv  = (unsigned short*)ws;                // 150,994,944 B
  unsigned short* attn = (unsigned short*)(ws + 150994944);  //  50,331,648 B
  unsigned short* xbf  = attn;  // aliased: x_bf16 dead before attn is written
  float* kvP   = (float*)(ws + 150994944);  // aliased: partials dead before attn
  float* kvG   = (float*)(ws + 201326592);                   //   1,597,440 B
  float* qkvb  = (float*)(ws + 202924032);
  float* projb = (float*)(ws + 202933248);
  unsigned short* wbf  = (unsigned short*)(ws + 202936320);  //   3,538,944 B
  unsigned short* pwbf = (unsigned short*)(ws + 206475264);  //   1,179,648 B

  // allow 128 KiB dynamic LDS for the 8-phase GEMM
  hipFuncSetAttribute(reinterpret_cast<const void*>(&gemm256<1>),
                      hipFuncAttributeMaxDynamicSharedMemorySize, 131072);
  hipFuncSetAttribute(reinterpret_cast<const void*>(&gemm256<0>),
                      hipFuncAttributeMaxDynamicSharedMemorySize, 131072);

  f32_to_bf16<<<dim3(12288), dim3(256), 0, stream>>>(x, xbf, 25165824);
  prep<<<dim3(1161), dim3(256), 0, stream>>>(qkv_w, proj_w, q_bias, v_bias,
                                             proj_b, wbf, pwbf, qkvb, projb);
  // qkv = x @ qkv_w^T + qkv_bias (M=32768, K=768, Nout=2304), bf16 out
  // grid 1152 = 128 bm x 9 bn (256x256 tiles), XCD-swizzled (1152 % 8 == 0)
  gemm256<1><<<dim3(1152), dim3(512), 131072, stream>>>(xbf, wbf, qkvb, qkv,
                                                        768, 2304, 9, 12);
  // NOTE: xbf (== kvP region) is dead from here on.
  pass_a<<<dim3(96, SPLIT_A), dim3(256), 0, stream>>>(qkv, rope, kvP);
  reduce_kv<<<dim3(1560), dim3(256), 0, stream>>>(kvP, kvG);
  pass_b<<<dim3(96, 16), dim3(256), 0, stream>>>(qkv, rope, kvG, attn);
  ln_kernel<<<dim3(32768), dim3(256), 0, stream>>>(attn, norm_g, norm_b);
  // out = ln @ proj_w^T + proj_b (M=32768, K=768, Nout=768) -> d_out fp32
  // grid 384 = 128 bm x 3 bn, XCD-swizzled (384 % 8 == 0)
  gemm256<0><<<dim3(384), dim3(512), 131072, stream>>>(attn, pwbf, projb, d_out,
                                                       768, 768, 3, 12);
}

// Round 9
// 562.109 us; speedup vs baseline: 1.0568x; 1.0568x over previous
//
#include <hip/hip_runtime.h>
#include <stdint.h>

// ---------------------------------------------------------------------------
// EvaLinearAttention on MI355X (gfx950).
// B=8, N=4096, C=768, H=12, D=64, npt=1. I/O fp32; GEMMs bf16 MFMA.
// R1: pass_a 16-way token split. 875 -> 666us.
// R2: XCD swizzle on GEMMs. 666 -> 658.
// R3: BK=64 2-phase: occupancy loss (reverted).
// R4: MFMA pass_b kept; packed epilogue at 128^2 cost VGPR (reverted).
// R5/R6: composition -> 583us. QKV gemm 194us.
// R7: 8-phase 256^2 QKV: loop fine (conflicts 0, VALUBusy 15%) but scalar
//     2B epilogue caused write RMW amplification (WRITE 187->263MB) eating
//     the schedule gain; proj 384-block tail cost ~11us. 594us.
// R8: gemm256 epilogue -> transposed QUAD (R4-verified mapping) +
//     LDS-staged coalesced C writeout (full 64B lines, 128KiB tile reuses
//     the dbuf LDS after the final barrier); proj reverted to R6 gemm_bt<0>.
//     (R8 bench was an infra failure; resubmitted unchanged.)
// ---------------------------------------------------------------------------

typedef __attribute__((ext_vector_type(8))) short short8;
typedef __attribute__((ext_vector_type(4))) float floatx4;

#define SPLIT_A 16
#define TILES_PER_BLK (32 / SPLIT_A)

#define SBAR()  do { asm volatile("" ::: "memory"); __builtin_amdgcn_s_barrier(); asm volatile("" ::: "memory"); } while (0)
#define LGKM0() do { asm volatile("s_waitcnt lgkmcnt(0)" ::: "memory"); __builtin_amdgcn_sched_barrier(0); } while (0)
#define WAITV6() asm volatile("s_waitcnt vmcnt(6)" ::: "memory")
#define WAITV0() asm volatile("s_waitcnt vmcnt(0)" ::: "memory")

__device__ __forceinline__ float b2f(unsigned short u) {
  union { unsigned int i; float f; } v; v.i = ((unsigned int)u) << 16; return v.f;
}
__device__ __forceinline__ unsigned short f2b(float f) {
  union { float f; unsigned int i; } v; v.f = f;
  unsigned int i = v.i;
  unsigned int r = (i + 0x7FFFu + ((i >> 16) & 1u)) >> 16;  // RNE
  return (unsigned short)r;
}
__device__ __forceinline__ void unpack2(unsigned int u, float& a, float& b) {
  union { unsigned int i; float f; } x, y;
  x.i = u << 16; y.i = u & 0xFFFF0000u;
  a = x.f; b = y.f;
}

__device__ __forceinline__ void stage16(const void* g, void* l) {
#if defined(__has_builtin) && __has_builtin(__builtin_amdgcn_global_load_lds)
  __builtin_amdgcn_global_load_lds(
      (const __attribute__((address_space(1))) unsigned int*)g,
      (__attribute__((address_space(3))) unsigned int*)l, 16, 0, 0);
#else
  *(uint4*)l = *(const uint4*)g;
#endif
}

// ---------------------------------------------------------------------------
__global__ __launch_bounds__(256) void f32_to_bf16(
    const float* __restrict__ in, unsigned short* __restrict__ out, int n) {
  const int i = (blockIdx.x * 256 + threadIdx.x) * 8;
  if (i + 7 < n) {
    float4 a = *(const float4*)(in + i);
    float4 b = *(const float4*)(in + i + 4);
    unsigned short tmp[8] = {f2b(a.x), f2b(a.y), f2b(a.z), f2b(a.w),
                             f2b(b.x), f2b(b.y), f2b(b.z), f2b(b.w)};
    *(uint4*)(out + i) = *(uint4*)tmp;
  }
}

// ---------------------------------------------------------------------------
// prep: convert qkv_w and proj_w to bf16, build fused qkv bias + proj bias.
// ---------------------------------------------------------------------------
__global__ __launch_bounds__(256) void prep(
    const float* __restrict__ w, const float* __restrict__ pw,
    const float* __restrict__ qb, const float* __restrict__ vb,
    const float* __restrict__ pb,
    unsigned short* __restrict__ wbf, unsigned short* __restrict__ pwbf,
    float* __restrict__ qkvb, float* __restrict__ projb) {
  const int blk = blockIdx.x, t = threadIdx.x;
  if (blk < 1152) {
    const float* src = (blk < 864) ? w : pw;
    unsigned short* dst = (blk < 864) ? wbf : pwbf;
    const int i = ((blk < 864 ? blk : blk - 864) * 256 + t) * 8;
    float4 a = *(const float4*)(src + i);
    float4 b = *(const float4*)(src + i + 4);
    unsigned short tmp[8] = {f2b(a.x), f2b(a.y), f2b(a.z), f2b(a.w),
                             f2b(b.x), f2b(b.y), f2b(b.z), f2b(b.w)};
    *(uint4*)(dst + i) = *(uint4*)tmp;
  } else {
    const int i = (blk - 1152) * 256 + t;
    if (i < 2304) qkvb[i] = (i < 768) ? qb[i] : (i >= 1536 ? vb[i - 1536] : 0.f);
    if (i < 768) projb[i] = pb[i];
  }
}

// ---------------------------------------------------------------------------
// 8-phase 256x256 bf16 GEMM (bf16 out), B^T. See R7 schedule comment.
// R8 epilogue: transposed QUAD (mfma(bfr,afr) -> lane owns 4 consecutive
// output cols; R4-harness-verified mapping), stage C tile into the freed
// 128KiB dbuf LDS (16B-chunk XOR swizzle), copy out full contiguous rows.
// ---------------------------------------------------------------------------
__global__ __launch_bounds__(512, 2) void gemm256(
    const unsigned short* __restrict__ A, const unsigned short* __restrict__ W,
    const float* __restrict__ bias, unsigned short* __restrict__ Out,
    int K, int Nout, int nbn, int NT) {
  extern __shared__ __align__(16) unsigned short lds[];  // 131072 B
  const int nwg = gridDim.x;
  const int orig = blockIdx.x;
  const int wg = (orig & 7) * (nwg >> 3) + (orig >> 3);  // bijective: nwg%8==0
  const int bm = wg / nbn, bn = wg - bm * nbn;
  const int t = threadIdx.x;
  const int lane = t & 63, wave = t >> 6;
  const int wr = wave >> 2, wc = wave & 3;
  const int mr = lane & 15, kq8 = lane >> 4;

  const int rh0 = t >> 3, sl0 = t & 7;
  const size_t growA = (size_t)bm * 256;
  const size_t growB = (size_t)bn * 256;

  #define STAGE_HALF(buf, op, G, grow, k0, half)                               \
    do {                                                                       \
      const int row0_ = (half)*128 + rh0;                                      \
      const int row1_ = row0_ + 64;                                            \
      const unsigned short* s0_ =                                              \
          (G) + ((grow) + row0_) * (size_t)K + (k0) + ((sl0 ^ (row0_ & 7)) * 8);\
      const unsigned short* s1_ =                                              \
          (G) + ((grow) + row1_) * (size_t)K + (k0) + ((sl0 ^ (row1_ & 7)) * 8);\
      unsigned short* d0_ = lds + (buf)*32768 + (op)*16384 + (half)*8192 + t*8;\
      stage16(s0_, d0_);                                                       \
      stage16(s1_, d0_ + 4096);                                                \
    } while (0)

  floatx4 acc[8][4] = {};
  short8 afr[4][2], bfr[4][2];

  #define RD_A(buf, i, kk)                                                     \
    (*(const short8*)&lds[(buf)*32768 + (wr*128 + (i)*16 + mr)*64 +            \
        ((((kk)*4 + kq8) ^ ((wr*128 + (i)*16 + mr) & 7)) * 8)])
  #define RD_B(buf, j, kk)                                                     \
    (*(const short8*)&lds[(buf)*32768 + 16384 + (wc*64 + (j)*16 + mr)*64 +     \
        ((((kk)*4 + kq8) ^ ((wc*64 + (j)*16 + mr) & 7)) * 8)])

  // Transposed operand order (R4-verified): D-row=W-row=out COL quad,
  // D-col=A-row=out ROW.
  #define QUAD(ih, jh)                                                         \
    do {                                                                       \
      __builtin_amdgcn_s_setprio(1);                                           \
      _Pragma("unroll")                                                        \
      for (int i_ = 0; i_ < 4; i_++)                                           \
        _Pragma("unroll")                                                      \
        for (int jr_ = 0; jr_ < 2; jr_++)                                      \
          _Pragma("unroll")                                                    \
          for (int kk_ = 0; kk_ < 2; kk_++)                                    \
            acc[(ih)*4 + i_][(jh)*2 + jr_] =                                   \
                __builtin_amdgcn_mfma_f32_16x16x32_bf16(                       \
                    bfr[(jh)*2 + jr_][kk_], afr[i_][kk_],                      \
                    acc[(ih)*4 + i_][(jh)*2 + jr_], 0, 0, 0);                  \
      __builtin_amdgcn_s_setprio(0);                                           \
    } while (0)

  // ---- prologue: tile0 -> buf0 (4 halves); tile1 -> buf1 (B0,B1,A0) ----
  STAGE_HALF(0, 0, A, growA, 0, 0);
  STAGE_HALF(0, 0, A, growA, 0, 1);
  STAGE_HALF(0, 1, W, growB, 0, 0);
  STAGE_HALF(0, 1, W, growB, 0, 1);
  STAGE_HALF(1, 1, W, growB, 64, 0);
  STAGE_HALF(1, 1, W, growB, 64, 1);
  STAGE_HALF(1, 0, A, growA, 64, 0);
  WAITV6();
  SBAR();

  const int NI = NT >> 1;
  for (int it = 0; it < NI; ++it) {
    const int ta = 2 * it, tb = ta + 1;
    const int kA = (ta + 2) * 64, kB = (tb + 2) * 64;
    const bool gA = (ta + 2) < NT, gB = (tb + 2) < NT;
    // ---- P1: buf0 Q00 ----
#pragma unroll
    for (int i = 0; i < 4; i++) { afr[i][0] = RD_A(0, i, 0); afr[i][1] = RD_A(0, i, 1); }
#pragma unroll
    for (int j = 0; j < 4; j++) { bfr[j][0] = RD_B(0, j, 0); bfr[j][1] = RD_B(0, j, 1); }
    STAGE_HALF(1, 0, A, growA, tb * 64, 1);
    SBAR(); LGKM0();
    QUAD(0, 0);
    SBAR();
    // ---- P2: buf0 Q01 ----
    if (gA) STAGE_HALF(0, 1, W, growB, kA, 0);
    SBAR();
    QUAD(0, 1);
    SBAR();
    // ---- P3: buf0 Q10 ----
#pragma unroll
    for (int i = 0; i < 4; i++) { afr[i][0] = RD_A(0, i + 4, 0); afr[i][1] = RD_A(0, i + 4, 1); }
    if (gA) STAGE_HALF(0, 1, W, growB, kA, 1);
    SBAR(); LGKM0();
    QUAD(1, 0);
    SBAR();
    // ---- P4: buf0 Q11 ; wait tb complete ----
    if (gA) STAGE_HALF(0, 0, A, growA, kA, 0);
    SBAR();
    QUAD(1, 1);
    if (gA) WAITV6(); else WAITV0();
    SBAR();
    // ---- P5: buf1 Q00 ----
#pragma unroll
    for (int i = 0; i < 4; i++) { afr[i][0] = RD_A(1, i, 0); afr[i][1] = RD_A(1, i, 1); }
#pragma unroll
    for (int j = 0; j < 4; j++) { bfr[j][0] = RD_B(1, j, 0); bfr[j][1] = RD_B(1, j, 1); }
    if (gA) STAGE_HALF(0, 0, A, growA, kA, 1);
    SBAR(); LGKM0();
    QUAD(0, 0);
    SBAR();
    // ---- P6: buf1 Q01 ----
    if (gB) STAGE_HALF(1, 1, W, growB, kB, 0);
    SBAR();
    QUAD(0, 1);
    SBAR();
    // ---- P7: buf1 Q10 ----
#pragma unroll
    for (int i = 0; i < 4; i++) { afr[i][0] = RD_A(1, i + 4, 0); afr[i][1] = RD_A(1, i + 4, 1); }
    if (gB) STAGE_HALF(1, 1, W, growB, kB, 1);
    SBAR(); LGKM0();
    QUAD(1, 0);
    SBAR();
    // ---- P8: buf1 Q11 ; wait ta+2 complete ----
    if (gB) STAGE_HALF(1, 0, A, growA, kB, 0);
    SBAR();
    QUAD(1, 1);
    if (gB) WAITV6(); else WAITV0();
    SBAR();
  }

  // ---- epilogue: stage C (bf16, +bias) into LDS [256][256] w/ chunk XOR ----
  // transposed D: row = wr*128 + i*16 + (lane&15),
  //               col = wc*64 + j*16 + (lane>>4)*4 + r  (4 consecutive cols)
  const int fr = lane & 15, fq4 = (lane >> 4) * 4;
#pragma unroll
  for (int i = 0; i < 8; i++) {
    const int lrow = wr * 128 + i * 16 + fr;
#pragma unroll
    for (int j = 0; j < 4; j++) {
      const int colu = wc * 64 + j * 16 + fq4;          // ushort col in tile
      const float4 bv = *(const float4*)&bias[bn * 256 + colu];
      unsigned short pk[4] = {f2b(acc[i][j][0] + bv.x), f2b(acc[i][j][1] + bv.y),
                              f2b(acc[i][j][2] + bv.z), f2b(acc[i][j][3] + bv.w)};
      const int chunk = colu >> 3;                       // 16B chunk index
      const int low = colu & 7;                          // 0 or 4 (8B half)
      *(uint2*)&lds[lrow * 256 + ((chunk ^ (lrow & 7)) << 3) + low] =
          *(const uint2*)pk;
    }
  }
  SBAR();
  // ---- copy out: full contiguous 512B rows (all 64B lines full) ----
#pragma unroll
  for (int p = 0; p < 16; p++) {
    const int row = p * 16 + (t >> 5);
    const int chunk = t & 31;
    uint4 v = *(const uint4*)&lds[row * 256 + ((chunk ^ (row & 7)) << 3)];
    *(uint4*)(Out + (size_t)(bm * 256 + row) * Nout + bn * 256 + chunk * 8) = v;
  }
  #undef STAGE_HALF
  #undef RD_A
  #undef RD_B
  #undef QUAD
}

// ---------------------------------------------------------------------------
// bf16 GEMM, B^T (R6-verified form): 128x128 tile, BK=32, VGPR 84,
// mfma(af,bfr), scalar stores (fp32 out = full 64B lines). XCD swizzle.
// Used for the proj GEMM (fp32 out).
// ---------------------------------------------------------------------------
template <int OUT_BF16>
__global__ __launch_bounds__(256) void gemm_bt(
    const unsigned short* __restrict__ A, const unsigned short* __restrict__ W,
    const float* __restrict__ bias, void* __restrict__ Out,
    int M, int K, int Nout, int nbn) {
  __shared__ __align__(16) unsigned short sA[128 * 32];
  __shared__ __align__(16) unsigned short sB[128 * 32];
  const int nwg = gridDim.x;
  const int orig = blockIdx.x;
  const int wg = (orig & 7) * (nwg >> 3) + (orig >> 3);
  const int bm = wg / nbn;
  const int bn = wg - bm * nbn;
  const int t = threadIdx.x;
  const int lane = t & 63, wave = t >> 6;
  const int wm = (wave >> 1) * 64, wn = (wave & 1) * 64;
  const int lr = t >> 2;
  const int lc = (t & 3) * 8;
  const size_t baseA = (size_t)(bm * 128 + lr) * K + lc;
  const size_t baseB = (size_t)(bn * 128 + lr) * K + lc;
  floatx4 acc[4][4] = {};

  const int mr = lane & 15, kq = (lane >> 4) * 8;
  for (int k0 = 0; k0 < K; k0 += 32) {
    stage16(A + baseA + k0, &sA[t * 8]);
    stage16(A + baseA + (size_t)64 * K + k0, &sA[2048 + t * 8]);
    stage16(W + baseB + k0, &sB[t * 8]);
    stage16(W + baseB + (size_t)64 * K + k0, &sB[2048 + t * 8]);
    __syncthreads();
    short8 af[4], bfr[4];
#pragma unroll
    for (int i = 0; i < 4; i++) af[i] = *(const short8*)&sA[(wm + i * 16 + mr) * 32 + kq];
#pragma unroll
    for (int j = 0; j < 4; j++) bfr[j] = *(const short8*)&sB[(wn + j * 16 + mr) * 32 + kq];
#pragma unroll
    for (int i = 0; i < 4; i++)
#pragma unroll
      for (int j = 0; j < 4; j++)
        acc[i][j] = __builtin_amdgcn_mfma_f32_16x16x32_bf16(af[i], bfr[j], acc[i][j], 0, 0, 0);
    __syncthreads();
  }

  const int mr4 = (lane >> 4) * 4, nc = lane & 15;
#pragma unroll
  for (int j = 0; j < 4; j++) {
    const int gc = bn * 128 + wn + j * 16 + nc;
    const float bv = bias[gc];
#pragma unroll
    for (int i = 0; i < 4; i++) {
      const int gr0 = bm * 128 + wm + i * 16 + mr4;
#pragma unroll
      for (int r = 0; r < 4; r++) {
        float v = acc[i][j][r] + bv;
        if (OUT_BF16)
          ((unsigned short*)Out)[(size_t)(gr0 + r) * Nout + gc] = f2b(v);
        else
          ((float*)Out)[(size_t)(gr0 + r) * Nout + gc] = v;
      }
    }
  }
}

// ---------------------------------------------------------------------------
// pass_a (split fp32): one block per (bh, split); 2 tiles of 128 tokens.
// ---------------------------------------------------------------------------
__global__ __launch_bounds__(256) void pass_a(
    const unsigned short* __restrict__ qkv, const float* __restrict__ rope,
    float* __restrict__ kvP) {
  __shared__ float sphi[128 * 65];
  __shared__ __align__(16) unsigned short sv[128 * 64];
  const int bh = blockIdx.x, b = bh / 12, h = bh % 12;
  const int sp = blockIdx.y;
  const int t = threadIdx.x;
  const int lane = t & 63, wave = t >> 6;
  const int dg = lane >> 2;
  const int eg = lane & 3;
  float acc[4][16] = {};
  float ks4[4] = {};

  const int tile0 = sp * TILES_PER_BLK;
  for (int tile = tile0; tile < tile0 + TILES_PER_BLK; tile++) {
    __syncthreads();
    if (t < 128) {
      const int n = tile * 128 + t;
      const size_t rowb = (size_t)(b * 4096 + n) * 2304;
      const unsigned short* kp = qkv + rowb + 768 + h * 64;
      float kk[64];
#pragma unroll
      for (int c = 0; c < 8; c++) {
        uint4 u = *(const uint4*)(kp + c * 8);
        unpack2(u.x, kk[c * 8 + 0], kk[c * 8 + 1]);
        unpack2(u.y, kk[c * 8 + 2], kk[c * 8 + 3]);
        unpack2(u.z, kk[c * 8 + 4], kk[c * 8 + 5]);
        unpack2(u.w, kk[c * 8 + 6], kk[c * 8 + 7]);
      }
      if (n > 0) {
        const float* rp = rope + (size_t)(n - 1) * 128;
#pragma unroll
        for (int c = 0; c < 8; c++) {
          float sn[8], cs[8];
          *(float4*)&sn[0] = *(const float4*)(rp + c * 8);
          *(float4*)&sn[4] = *(const float4*)(rp + c * 8 + 4);
          *(float4*)&cs[0] = *(const float4*)(rp + 64 + c * 8);
          *(float4*)&cs[4] = *(const float4*)(rp + 64 + c * 8 + 4);
#pragma unroll
          for (int i = 0; i < 4; i++) {
            float e = kk[c * 8 + 2 * i], o = kk[c * 8 + 2 * i + 1];
            kk[c * 8 + 2 * i] = e * cs[2 * i] - o * sn[2 * i];
            kk[c * 8 + 2 * i + 1] = o * cs[2 * i + 1] + e * sn[2 * i + 1];
          }
        }
      }
      float mx = kk[0];
#pragma unroll
      for (int i = 1; i < 64; i++) mx = fmaxf(mx, kk[i]);
      float s = 0.f;
#pragma unroll
      for (int i = 0; i < 64; i++) { float e = __expf(kk[i] - mx); kk[i] = e; s += e; }
      const float inv = 1.f / s;
#pragma unroll
      for (int d = 0; d < 64; d++) sphi[t * 65 + d] = kk[d] * inv;
      const unsigned short* vp = qkv + rowb + 1536 + h * 64;
#pragma unroll
      for (int c = 0; c < 8; c++)
        *(uint4*)&sv[t * 64 + c * 8] = *(const uint4*)(vp + c * 8);
    }
    __syncthreads();
    const int n0 = wave * 32;
    for (int nn = n0; nn < n0 + 32; nn++) {
      float p[4];
#pragma unroll
      for (int i = 0; i < 4; i++) p[i] = sphi[nn * 65 + dg * 4 + i];
#pragma unroll
      for (int i = 0; i < 4; i++) ks4[i] += p[i];
      float vv[16];
      {
        uint4 u0 = *(const uint4*)&sv[nn * 64 + eg * 16];
        uint4 u1 = *(const uint4*)&sv[nn * 64 + eg * 16 + 8];
        unpack2(u0.x, vv[0], vv[1]);   unpack2(u0.y, vv[2], vv[3]);
        unpack2(u0.z, vv[4], vv[5]);   unpack2(u0.w, vv[6], vv[7]);
        unpack2(u1.x, vv[8], vv[9]);   unpack2(u1.y, vv[10], vv[11]);
        unpack2(u1.z, vv[12], vv[13]); unpack2(u1.w, vv[14], vv[15]);
      }
#pragma unroll
      for (int i = 0; i < 4; i++)
#pragma unroll
        for (int j = 0; j < 16; j++)
          acc[i][j] += p[i] * vv[j];
    }
  }

  __syncthreads();
  float* sred = sphi;
  float* o = kvP + ((size_t)bh * SPLIT_A + sp) * 4160;
#pragma unroll
  for (int half = 0; half < 2; half++) {
    if (wave != 0) {
      float* row = &sred[((wave - 1) * 64 + lane) * 33];
#pragma unroll
      for (int i = 0; i < 4; i++)
#pragma unroll
        for (int jj = 0; jj < 8; jj++) row[i * 8 + jj] = acc[i][half * 8 + jj];
    }
    __syncthreads();
    if (wave == 0) {
#pragma unroll
      for (int jj = 0; jj < 8; jj++) {
        float4 s4;
        float sv4[4];
#pragma unroll
        for (int i = 0; i < 4; i++) {
          float s = acc[i][half * 8 + jj];
#pragma unroll
          for (int w = 0; w < 3; w++) s += sred[(w * 64 + lane) * 33 + i * 8 + jj];
          sv4[i] = s;
        }
        s4.x = sv4[0]; s4.y = sv4[1]; s4.z = sv4[2]; s4.w = sv4[3];
        const int e = eg * 16 + half * 8 + jj;
        *(float4*)&o[e * 64 + dg * 4] = s4;
      }
    }
    __syncthreads();
  }
  if (wave != 0) {
#pragma unroll
    for (int i = 0; i < 4; i++) sred[((wave - 1) * 64 + lane) * 5 + i] = ks4[i];
  }
  __syncthreads();
  if (wave == 0 && eg == 0) {
    float4 s4;
    float sv4[4];
#pragma unroll
    for (int i = 0; i < 4; i++) {
      float s = ks4[i];
#pragma unroll
      for (int w = 0; w < 3; w++) s += sred[(w * 64 + lane) * 5 + i];
      sv4[i] = s;
    }
    s4.x = sv4[0]; s4.y = sv4[1]; s4.z = sv4[2]; s4.w = sv4[3];
    *(float4*)&o[4096 + dg * 4] = s4;
  }
}

// ---------------------------------------------------------------------------
__global__ __launch_bounds__(256) void reduce_kv(
    const float* __restrict__ kvP, float* __restrict__ kvG) {
  const int i = blockIdx.x * 256 + threadIdx.x;
  if (i >= 96 * 4160) return;
  const int bh = i / 4160, r = i - bh * 4160;
  const float* p = kvP + (size_t)bh * SPLIT_A * 4160 + r;
  float s = 0.f;
#pragma unroll
  for (int sp = 0; sp < SPLIT_A; sp++) s += p[(size_t)sp * 4160];
  kvG[i] = s;
}

// ---------------------------------------------------------------------------
// pass_b (MFMA): phi/kv bf16 in swizzled LDS; 32 MFMA/wave. (R6-verified)
// ---------------------------------------------------------------------------
__global__ __launch_bounds__(256) void pass_b(
    const unsigned short* __restrict__ qkv, const float* __restrict__ rope,
    const float* __restrict__ kvG, unsigned short* __restrict__ attn) {
  __shared__ __align__(16) unsigned short sp_[256 * 64];
  __shared__ __align__(16) unsigned short skv[64 * 64];
  __shared__ float szi[256];
  __shared__ float sks[64];
  const int bh = blockIdx.x, b = bh / 12, h = bh % 12;
  const int t = threadIdx.x;
  const float* kvb = kvG + (size_t)bh * 4160;

  {
    const int e = t >> 2, q = t & 3;
    const float* src = kvb + e * 64 + q * 16;
    unsigned short tmp[16];
#pragma unroll
    for (int i = 0; i < 16; i++) tmp[i] = f2b(src[i]);
    *(uint4*)&skv[e * 64 + (((q * 2) ^ (e & 7)) * 8)] = *(uint4*)&tmp[0];
    *(uint4*)&skv[e * 64 + (((q * 2 + 1) ^ (e & 7)) * 8)] = *(uint4*)&tmp[8];
  }
  if (t < 64) sks[t] = kvb[4096 + t];
  __syncthreads();

  const int n = blockIdx.y * 256 + t;
  const size_t rowb = (size_t)(b * 4096 + n) * 2304;
  const unsigned short* qp = qkv + rowb + h * 64;
  float ph[64];
#pragma unroll
  for (int c = 0; c < 8; c++) {
    uint4 u = *(const uint4*)(qp + c * 8);
    unpack2(u.x, ph[c * 8 + 0], ph[c * 8 + 1]);
    unpack2(u.y, ph[c * 8 + 2], ph[c * 8 + 3]);
    unpack2(u.z, ph[c * 8 + 4], ph[c * 8 + 5]);
    unpack2(u.w, ph[c * 8 + 6], ph[c * 8 + 7]);
  }
  if (n > 0) {
    const float* rp = rope + (size_t)(n - 1) * 128;
#pragma unroll
    for (int c = 0; c < 8; c++) {
      float sn[8], cs[8];
      *(float4*)&sn[0] = *(const float4*)(rp + c * 8);
      *(float4*)&sn[4] = *(const float4*)(rp + c * 8 + 4);
      *(float4*)&cs[0] = *(const float4*)(rp + 64 + c * 8);
      *(float4*)&cs[4] = *(const float4*)(rp + 64 + c * 8 + 4);
#pragma unroll
      for (int i = 0; i < 4; i++) {
        float e = ph[c * 8 + 2 * i], o = ph[c * 8 + 2 * i + 1];
        ph[c * 8 + 2 * i] = e * cs[2 * i] - o * sn[2 * i];
        ph[c * 8 + 2 * i + 1] = o * cs[2 * i + 1] + e * sn[2 * i + 1];
      }
    }
  }
  float mx = ph[0];
#pragma unroll
  for (int i = 1; i < 64; i++) mx = fmaxf(mx, ph[i]);
  float s = 0.f;
#pragma unroll
  for (int i = 0; i < 64; i++) { float e = __expf(ph[i] - mx); ph[i] = e; s += e; }
  const float inv = 1.f / s;
  float z = 0.f;
#pragma unroll
  for (int i = 0; i < 64; i++) { ph[i] *= inv; z += ph[i] * sks[i]; }
  szi[t] = 1.f / (z + 1e-5f);

#pragma unroll
  for (int sl = 0; sl < 8; sl += 2) {
    unsigned short tmp[16];
#pragma unroll
    for (int i = 0; i < 16; i++) tmp[i] = f2b(ph[sl * 8 + i]);
    *(uint4*)&sp_[t * 64 + ((sl ^ (t & 7)) * 8)] = *(uint4*)&tmp[0];
    *(uint4*)&sp_[t * 64 + (((sl + 1) ^ (t & 7)) * 8)] = *(uint4*)&tmp[8];
  }
  __syncthreads();

  const int lane = t & 63, wv = t >> 6;
  const int fr = lane & 15, fq = lane >> 4;
  floatx4 acc[4][4] = {};
#pragma unroll
  for (int kk = 0; kk < 2; kk++) {
    short8 kvf[4], pf[4];
#pragma unroll
    for (int j = 0; j < 4; j++) {
      const int e = j * 16 + fr;
      kvf[j] = *(const short8*)&skv[e * 64 + (((kk * 4 + fq) ^ (e & 7)) * 8)];
    }
#pragma unroll
    for (int i = 0; i < 4; i++) {
      const int tok = wv * 64 + i * 16 + fr;
      pf[i] = *(const short8*)&sp_[tok * 64 + (((kk * 4 + fq) ^ (tok & 7)) * 8)];
    }
#pragma unroll
    for (int i = 0; i < 4; i++)
#pragma unroll
      for (int j = 0; j < 4; j++)
        acc[i][j] = __builtin_amdgcn_mfma_f32_16x16x32_bf16(kvf[j], pf[i], acc[i][j], 0, 0, 0);
  }

#pragma unroll
  for (int i = 0; i < 4; i++) {
    const int tokl = wv * 64 + i * 16 + fr;
    const float zi = szi[tokl];
    unsigned short* orow =
        attn + (size_t)(b * 4096 + blockIdx.y * 256 + tokl) * 768 + h * 64;
#pragma unroll
    for (int j = 0; j < 4; j++) {
      const int e0 = j * 16 + fq * 4;
      unsigned short pk[4] = {f2b(acc[i][j][0] * zi), f2b(acc[i][j][1] * zi),
                              f2b(acc[i][j][2] * zi), f2b(acc[i][j][3] * zi)};
      *(uint2*)(orow + e0) = *(const uint2*)pk;
    }
  }
}

// ---------------------------------------------------------------------------
__global__ __launch_bounds__(256) void ln_kernel(
    unsigned short* __restrict__ buf, const float* __restrict__ g,
    const float* __restrict__ be) {
  const int row = blockIdx.x;
  const int t = threadIdx.x;
  unsigned short* p = buf + (size_t)row * 768;
  const float x0 = b2f(p[t]), x1 = b2f(p[t + 256]), x2 = b2f(p[t + 512]);
  float s = x0 + x1 + x2;
  float ss = x0 * x0 + x1 * x1 + x2 * x2;
#pragma unroll
  for (int m = 1; m < 64; m <<= 1) { s += __shfl_xor(s, m); ss += __shfl_xor(ss, m); }
  __shared__ float red[8];
  const int wave = t >> 6, lane = t & 63;
  if (lane == 0) { red[wave] = s; red[4 + wave] = ss; }
  __syncthreads();
  s = red[0] + red[1] + red[2] + red[3];
  ss = red[4] + red[5] + red[6] + red[7];
  const float mean = s * (1.f / 768.f);
  const float var = ss * (1.f / 768.f) - mean * mean;
  const float rsq = rsqrtf(var + 1e-5f);
  p[t] = f2b((x0 - mean) * rsq * g[t] + be[t]);
  p[t + 256] = f2b((x1 - mean) * rsq * g[t + 256] + be[t + 256]);
  p[t + 512] = f2b((x2 - mean) * rsq * g[t + 512] + be[t + 512]);
}

// ---------------------------------------------------------------------------
extern "C" void kernel_launch(void* const* d_in, const int* in_sizes, int n_in,
                              void* d_out, int out_size, void* d_ws, size_t ws_size,
                              hipStream_t stream) {
  (void)in_sizes; (void)n_in; (void)out_size; (void)ws_size;
  const float* x      = (const float*)d_in[0];
  const float* rope   = (const float*)d_in[1];
  const float* qkv_w  = (const float*)d_in[2];
  const float* q_bias = (const float*)d_in[3];
  const float* v_bias = (const float*)d_in[4];
  const float* norm_g = (const float*)d_in[5];
  const float* norm_b = (const float*)d_in[6];
  const float* proj_w = (const float*)d_in[7];
  const float* proj_b = (const float*)d_in[8];

  char* ws = (char*)d_ws;
  unsigned short* qkv  = (unsigned short*)ws;                // 150,994,944 B
  unsigned short* attn = (unsigned short*)(ws + 150994944);  //  50,331,648 B
  unsigned short* xbf  = attn;  // aliased: x_bf16 dead before attn is written
  float* kvP   = (float*)(ws + 150994944);  // aliased: partials dead before attn
  float* kvG   = (float*)(ws + 201326592);                   //   1,597,440 B
  float* qkvb  = (float*)(ws + 202924032);
  float* projb = (float*)(ws + 202933248);
  unsigned short* wbf  = (unsigned short*)(ws + 202936320);  //   3,538,944 B
  unsigned short* pwbf = (unsigned short*)(ws + 206475264);  //   1,179,648 B

  hipFuncSetAttribute(reinterpret_cast<const void*>(&gemm256),
                      hipFuncAttributeMaxDynamicSharedMemorySize, 131072);

  f32_to_bf16<<<dim3(12288), dim3(256), 0, stream>>>(x, xbf, 25165824);
  prep<<<dim3(1161), dim3(256), 0, stream>>>(qkv_w, proj_w, q_bias, v_bias,
                                             proj_b, wbf, pwbf, qkvb, projb);
  // qkv = x @ qkv_w^T + qkv_bias (M=32768, K=768, Nout=2304), bf16 out
  // grid 1152 = 128 bm x 9 bn (256x256 tiles), XCD-swizzled
  gemm256<<<dim3(1152), dim3(512), 131072, stream>>>(xbf, wbf, qkvb, qkv,
                                                     768, 2304, 9, 12);
  // NOTE: xbf (== kvP region) is dead from here on.
  pass_a<<<dim3(96, SPLIT_A), dim3(256), 0, stream>>>(qkv, rope, kvP);
  reduce_kv<<<dim3(1560), dim3(256), 0, stream>>>(kvP, kvG);
  pass_b<<<dim3(96, 16), dim3(256), 0, stream>>>(qkv, rope, kvG, attn);
  ln_kernel<<<dim3(32768), dim3(256), 0, stream>>>(attn, norm_g, norm_b);
  // out = ln @ proj_w^T + proj_b (M=32768, K=768, Nout=768) -> d_out fp32
  // grid 1536 = 6 bn x 256 bm (128x128 tiles), XCD-swizzled
  gemm_bt<0><<<dim3(1536), dim3(256), 0, stream>>>(attn, pwbf, projb, d_out,
                                                   32768, 768, 768, 6);
}

// Round 10
// 520.505 us; speedup vs baseline: 1.1413x; 1.0799x over previous
//
#include <hip/hip_runtime.h>
#include <stdint.h>

// ---------------------------------------------------------------------------
// EvaLinearAttention on MI355X (gfx950).
// B=8, N=4096, C=768, H=12, D=64, npt=1. I/O fp32; GEMMs bf16 MFMA.
// R1: pass_a 16-way token split. 875 -> 666us.
// R2: XCD swizzle on GEMMs. 666 -> 658.
// R3: BK=64 2-phase: occupancy loss (reverted).
// R4: MFMA pass_b kept; packed epilogue at 128^2 cost VGPR (reverted).
// R5/R6: composition -> 583us. QKV gemm 194us.
// R7: 8-phase 256^2 QKV: schedule fine but scalar epilogue write-RMW. 594.
// R9: gemm256 + transposed QUAD + LDS-staged coalesced C writeout:
//     WRITE 263->147MB (ideal), QKV 194->146us, MfmaUtil 33%. 562us.
// R10 (this): MFMA-ize pass_a. Old: fp32 vector outer-product (3.2 GFLOP on
//     VALU, half-idle producer waves, 3-stage LDS merge). New: 256-token
//     tile, ALL threads produce phi_k/v -> transpose-write bf16 into
//     [d][256]/[e][256] chunk-XOR LDS; each wave owns one 16-d block for
//     full K=256 (8 ksteps x 5 MFMA incl. ones-frag ksum); no merge.
// ---------------------------------------------------------------------------

typedef __attribute__((ext_vector_type(8))) short short8;
typedef __attribute__((ext_vector_type(4))) float floatx4;

#define SPLIT_A 16

#define SBAR()  do { asm volatile("" ::: "memory"); __builtin_amdgcn_s_barrier(); asm volatile("" ::: "memory"); } while (0)
#define LGKM0() do { asm volatile("s_waitcnt lgkmcnt(0)" ::: "memory"); __builtin_amdgcn_sched_barrier(0); } while (0)
#define WAITV6() asm volatile("s_waitcnt vmcnt(6)" ::: "memory")
#define WAITV0() asm volatile("s_waitcnt vmcnt(0)" ::: "memory")

__device__ __forceinline__ float b2f(unsigned short u) {
  union { unsigned int i; float f; } v; v.i = ((unsigned int)u) << 16; return v.f;
}
__device__ __forceinline__ unsigned short f2b(float f) {
  union { float f; unsigned int i; } v; v.f = f;
  unsigned int i = v.i;
  unsigned int r = (i + 0x7FFFu + ((i >> 16) & 1u)) >> 16;  // RNE
  return (unsigned short)r;
}
__device__ __forceinline__ void unpack2(unsigned int u, float& a, float& b) {
  union { unsigned int i; float f; } x, y;
  x.i = u << 16; y.i = u & 0xFFFF0000u;
  a = x.f; b = y.f;
}

__device__ __forceinline__ void stage16(const void* g, void* l) {
#if defined(__has_builtin) && __has_builtin(__builtin_amdgcn_global_load_lds)
  __builtin_amdgcn_global_load_lds(
      (const __attribute__((address_space(1))) unsigned int*)g,
      (__attribute__((address_space(3))) unsigned int*)l, 16, 0, 0);
#else
  *(uint4*)l = *(const uint4*)g;
#endif
}

// ---------------------------------------------------------------------------
__global__ __launch_bounds__(256) void f32_to_bf16(
    const float* __restrict__ in, unsigned short* __restrict__ out, int n) {
  const int i = (blockIdx.x * 256 + threadIdx.x) * 8;
  if (i + 7 < n) {
    float4 a = *(const float4*)(in + i);
    float4 b = *(const float4*)(in + i + 4);
    unsigned short tmp[8] = {f2b(a.x), f2b(a.y), f2b(a.z), f2b(a.w),
                             f2b(b.x), f2b(b.y), f2b(b.z), f2b(b.w)};
    *(uint4*)(out + i) = *(uint4*)tmp;
  }
}

// ---------------------------------------------------------------------------
// prep: convert qkv_w and proj_w to bf16, build fused qkv bias + proj bias.
// ---------------------------------------------------------------------------
__global__ __launch_bounds__(256) void prep(
    const float* __restrict__ w, const float* __restrict__ pw,
    const float* __restrict__ qb, const float* __restrict__ vb,
    const float* __restrict__ pb,
    unsigned short* __restrict__ wbf, unsigned short* __restrict__ pwbf,
    float* __restrict__ qkvb, float* __restrict__ projb) {
  const int blk = blockIdx.x, t = threadIdx.x;
  if (blk < 1152) {
    const float* src = (blk < 864) ? w : pw;
    unsigned short* dst = (blk < 864) ? wbf : pwbf;
    const int i = ((blk < 864 ? blk : blk - 864) * 256 + t) * 8;
    float4 a = *(const float4*)(src + i);
    float4 b = *(const float4*)(src + i + 4);
    unsigned short tmp[8] = {f2b(a.x), f2b(a.y), f2b(a.z), f2b(a.w),
                             f2b(b.x), f2b(b.y), f2b(b.z), f2b(b.w)};
    *(uint4*)(dst + i) = *(uint4*)tmp;
  } else {
    const int i = (blk - 1152) * 256 + t;
    if (i < 2304) qkvb[i] = (i < 768) ? qb[i] : (i >= 1536 ? vb[i - 1536] : 0.f);
    if (i < 768) projb[i] = pb[i];
  }
}

// ---------------------------------------------------------------------------
// 8-phase 256x256 bf16 GEMM (bf16 out), B^T. R9-verified.
// ---------------------------------------------------------------------------
__global__ __launch_bounds__(512, 2) void gemm256(
    const unsigned short* __restrict__ A, const unsigned short* __restrict__ W,
    const float* __restrict__ bias, unsigned short* __restrict__ Out,
    int K, int Nout, int nbn, int NT) {
  extern __shared__ __align__(16) unsigned short lds[];  // 131072 B
  const int nwg = gridDim.x;
  const int orig = blockIdx.x;
  const int wg = (orig & 7) * (nwg >> 3) + (orig >> 3);  // bijective: nwg%8==0
  const int bm = wg / nbn, bn = wg - bm * nbn;
  const int t = threadIdx.x;
  const int lane = t & 63, wave = t >> 6;
  const int wr = wave >> 2, wc = wave & 3;
  const int mr = lane & 15, kq8 = lane >> 4;

  const int rh0 = t >> 3, sl0 = t & 7;
  const size_t growA = (size_t)bm * 256;
  const size_t growB = (size_t)bn * 256;

  #define STAGE_HALF(buf, op, G, grow, k0, half)                               \
    do {                                                                       \
      const int row0_ = (half)*128 + rh0;                                      \
      const int row1_ = row0_ + 64;                                            \
      const unsigned short* s0_ =                                              \
          (G) + ((grow) + row0_) * (size_t)K + (k0) + ((sl0 ^ (row0_ & 7)) * 8);\
      const unsigned short* s1_ =                                              \
          (G) + ((grow) + row1_) * (size_t)K + (k0) + ((sl0 ^ (row1_ & 7)) * 8);\
      unsigned short* d0_ = lds + (buf)*32768 + (op)*16384 + (half)*8192 + t*8;\
      stage16(s0_, d0_);                                                       \
      stage16(s1_, d0_ + 4096);                                                \
    } while (0)

  floatx4 acc[8][4] = {};
  short8 afr[4][2], bfr[4][2];

  #define RD_A(buf, i, kk)                                                     \
    (*(const short8*)&lds[(buf)*32768 + (wr*128 + (i)*16 + mr)*64 +            \
        ((((kk)*4 + kq8) ^ ((wr*128 + (i)*16 + mr) & 7)) * 8)])
  #define RD_B(buf, j, kk)                                                     \
    (*(const short8*)&lds[(buf)*32768 + 16384 + (wc*64 + (j)*16 + mr)*64 +     \
        ((((kk)*4 + kq8) ^ ((wc*64 + (j)*16 + mr) & 7)) * 8)])

  // Transposed operand order (R4-verified): D-row=W-row=out COL quad,
  // D-col=A-row=out ROW.
  #define QUAD(ih, jh)                                                         \
    do {                                                                       \
      __builtin_amdgcn_s_setprio(1);                                           \
      _Pragma("unroll")                                                        \
      for (int i_ = 0; i_ < 4; i_++)                                           \
        _Pragma("unroll")                                                      \
        for (int jr_ = 0; jr_ < 2; jr_++)                                      \
          _Pragma("unroll")                                                    \
          for (int kk_ = 0; kk_ < 2; kk_++)                                    \
            acc[(ih)*4 + i_][(jh)*2 + jr_] =                                   \
                __builtin_amdgcn_mfma_f32_16x16x32_bf16(                       \
                    bfr[(jh)*2 + jr_][kk_], afr[i_][kk_],                      \
                    acc[(ih)*4 + i_][(jh)*2 + jr_], 0, 0, 0);                  \
      __builtin_amdgcn_s_setprio(0);                                           \
    } while (0)

  // ---- prologue: tile0 -> buf0 (4 halves); tile1 -> buf1 (B0,B1,A0) ----
  STAGE_HALF(0, 0, A, growA, 0, 0);
  STAGE_HALF(0, 0, A, growA, 0, 1);
  STAGE_HALF(0, 1, W, growB, 0, 0);
  STAGE_HALF(0, 1, W, growB, 0, 1);
  STAGE_HALF(1, 1, W, growB, 64, 0);
  STAGE_HALF(1, 1, W, growB, 64, 1);
  STAGE_HALF(1, 0, A, growA, 64, 0);
  WAITV6();
  SBAR();

  const int NI = NT >> 1;
  for (int it = 0; it < NI; ++it) {
    const int ta = 2 * it, tb = ta + 1;
    const int kA = (ta + 2) * 64, kB = (tb + 2) * 64;
    const bool gA = (ta + 2) < NT, gB = (tb + 2) < NT;
    // ---- P1: buf0 Q00 ----
#pragma unroll
    for (int i = 0; i < 4; i++) { afr[i][0] = RD_A(0, i, 0); afr[i][1] = RD_A(0, i, 1); }
#pragma unroll
    for (int j = 0; j < 4; j++) { bfr[j][0] = RD_B(0, j, 0); bfr[j][1] = RD_B(0, j, 1); }
    STAGE_HALF(1, 0, A, growA, tb * 64, 1);
    SBAR(); LGKM0();
    QUAD(0, 0);
    SBAR();
    // ---- P2: buf0 Q01 ----
    if (gA) STAGE_HALF(0, 1, W, growB, kA, 0);
    SBAR();
    QUAD(0, 1);
    SBAR();
    // ---- P3: buf0 Q10 ----
#pragma unroll
    for (int i = 0; i < 4; i++) { afr[i][0] = RD_A(0, i + 4, 0); afr[i][1] = RD_A(0, i + 4, 1); }
    if (gA) STAGE_HALF(0, 1, W, growB, kA, 1);
    SBAR(); LGKM0();
    QUAD(1, 0);
    SBAR();
    // ---- P4: buf0 Q11 ; wait tb complete ----
    if (gA) STAGE_HALF(0, 0, A, growA, kA, 0);
    SBAR();
    QUAD(1, 1);
    if (gA) WAITV6(); else WAITV0();
    SBAR();
    // ---- P5: buf1 Q00 ----
#pragma unroll
    for (int i = 0; i < 4; i++) { afr[i][0] = RD_A(1, i, 0); afr[i][1] = RD_A(1, i, 1); }
#pragma unroll
    for (int j = 0; j < 4; j++) { bfr[j][0] = RD_B(1, j, 0); bfr[j][1] = RD_B(1, j, 1); }
    if (gA) STAGE_HALF(0, 0, A, growA, kA, 1);
    SBAR(); LGKM0();
    QUAD(0, 0);
    SBAR();
    // ---- P6: buf1 Q01 ----
    if (gB) STAGE_HALF(1, 1, W, growB, kB, 0);
    SBAR();
    QUAD(0, 1);
    SBAR();
    // ---- P7: buf1 Q10 ----
#pragma unroll
    for (int i = 0; i < 4; i++) { afr[i][0] = RD_A(1, i + 4, 0); afr[i][1] = RD_A(1, i + 4, 1); }
    if (gB) STAGE_HALF(1, 1, W, growB, kB, 1);
    SBAR(); LGKM0();
    QUAD(1, 0);
    SBAR();
    // ---- P8: buf1 Q11 ; wait ta+2 complete ----
    if (gB) STAGE_HALF(1, 0, A, growA, kB, 0);
    SBAR();
    QUAD(1, 1);
    if (gB) WAITV6(); else WAITV0();
    SBAR();
  }

  // ---- epilogue: stage C (bf16, +bias) into LDS [256][256] w/ chunk XOR ----
  const int fr = lane & 15, fq4 = (lane >> 4) * 4;
#pragma unroll
  for (int i = 0; i < 8; i++) {
    const int lrow = wr * 128 + i * 16 + fr;
#pragma unroll
    for (int j = 0; j < 4; j++) {
      const int colu = wc * 64 + j * 16 + fq4;
      const float4 bv = *(const float4*)&bias[bn * 256 + colu];
      unsigned short pk[4] = {f2b(acc[i][j][0] + bv.x), f2b(acc[i][j][1] + bv.y),
                              f2b(acc[i][j][2] + bv.z), f2b(acc[i][j][3] + bv.w)};
      const int chunk = colu >> 3;
      const int low = colu & 7;
      *(uint2*)&lds[lrow * 256 + ((chunk ^ (lrow & 7)) << 3) + low] =
          *(const uint2*)pk;
    }
  }
  SBAR();
#pragma unroll
  for (int p = 0; p < 16; p++) {
    const int row = p * 16 + (t >> 5);
    const int chunk = t & 31;
    uint4 v = *(const uint4*)&lds[row * 256 + ((chunk ^ (row & 7)) << 3)];
    *(uint4*)(Out + (size_t)(bm * 256 + row) * Nout + bn * 256 + chunk * 8) = v;
  }
  #undef STAGE_HALF
  #undef RD_A
  #undef RD_B
  #undef QUAD
}

// ---------------------------------------------------------------------------
// bf16 GEMM, B^T (R6-verified form): 128x128 tile, BK=32, VGPR 84. Proj GEMM.
// ---------------------------------------------------------------------------
template <int OUT_BF16>
__global__ __launch_bounds__(256) void gemm_bt(
    const unsigned short* __restrict__ A, const unsigned short* __restrict__ W,
    const float* __restrict__ bias, void* __restrict__ Out,
    int M, int K, int Nout, int nbn) {
  __shared__ __align__(16) unsigned short sA[128 * 32];
  __shared__ __align__(16) unsigned short sB[128 * 32];
  const int nwg = gridDim.x;
  const int orig = blockIdx.x;
  const int wg = (orig & 7) * (nwg >> 3) + (orig >> 3);
  const int bm = wg / nbn;
  const int bn = wg - bm * nbn;
  const int t = threadIdx.x;
  const int lane = t & 63, wave = t >> 6;
  const int wm = (wave >> 1) * 64, wn = (wave & 1) * 64;
  const int lr = t >> 2;
  const int lc = (t & 3) * 8;
  const size_t baseA = (size_t)(bm * 128 + lr) * K + lc;
  const size_t baseB = (size_t)(bn * 128 + lr) * K + lc;
  floatx4 acc[4][4] = {};

  const int mr = lane & 15, kq = (lane >> 4) * 8;
  for (int k0 = 0; k0 < K; k0 += 32) {
    stage16(A + baseA + k0, &sA[t * 8]);
    stage16(A + baseA + (size_t)64 * K + k0, &sA[2048 + t * 8]);
    stage16(W + baseB + k0, &sB[t * 8]);
    stage16(W + baseB + (size_t)64 * K + k0, &sB[2048 + t * 8]);
    __syncthreads();
    short8 af[4], bfr[4];
#pragma unroll
    for (int i = 0; i < 4; i++) af[i] = *(const short8*)&sA[(wm + i * 16 + mr) * 32 + kq];
#pragma unroll
    for (int j = 0; j < 4; j++) bfr[j] = *(const short8*)&sB[(wn + j * 16 + mr) * 32 + kq];
#pragma unroll
    for (int i = 0; i < 4; i++)
#pragma unroll
      for (int j = 0; j < 4; j++)
        acc[i][j] = __builtin_amdgcn_mfma_f32_16x16x32_bf16(af[i], bfr[j], acc[i][j], 0, 0, 0);
    __syncthreads();
  }

  const int mr4 = (lane >> 4) * 4, nc = lane & 15;
#pragma unroll
  for (int j = 0; j < 4; j++) {
    const int gc = bn * 128 + wn + j * 16 + nc;
    const float bv = bias[gc];
#pragma unroll
    for (int i = 0; i < 4; i++) {
      const int gr0 = bm * 128 + wm + i * 16 + mr4;
#pragma unroll
      for (int r = 0; r < 4; r++) {
        float v = acc[i][j][r] + bv;
        if (OUT_BF16)
          ((unsigned short*)Out)[(size_t)(gr0 + r) * Nout + gc] = f2b(v);
        else
          ((float*)Out)[(size_t)(gr0 + r) * Nout + gc] = v;
      }
    }
  }
}

// ---------------------------------------------------------------------------
// pass_a (MFMA, R10): block = (bh, sp) covers 256 tokens. Every thread
// computes phi_k (rope+softmax, fp32) for its token, transpose-writes phi
// (bf16) into sphiT[d][256] and v into svT[e][256] (chunk-XOR c^(row&7),
// 16B chunks; 2-way banks everywhere). Then wave w owns d-rows
// [w*16,w*16+16): 8 ksteps x {1 A-frag, 4 B-frags, 4 MFMA, 1 ones-MFMA
// (ksum)}. mfma(af,bf) = D[a_row][b_row] (gemm_bt-verified). Direct float4
// partial stores to kvP; no cross-wave merge.
// ---------------------------------------------------------------------------
__global__ __launch_bounds__(256) void pass_a(
    const unsigned short* __restrict__ qkv, const float* __restrict__ rope,
    float* __restrict__ kvP) {
  __shared__ __align__(16) unsigned short sphiT[64 * 256];  // 32 KB [d][tok]
  __shared__ __align__(16) unsigned short svT[64 * 256];    // 32 KB [e][tok]
  const int bh = blockIdx.x, b = bh / 12, h = bh % 12;
  const int sp = blockIdx.y;
  const int t = threadIdx.x;

  // ---- producer: token n = sp*256 + t ----
  const int n = sp * 256 + t;
  const size_t rowb = (size_t)(b * 4096 + n) * 2304;
  const unsigned short* kp = qkv + rowb + 768 + h * 64;
  float kk[64];
#pragma unroll
  for (int c = 0; c < 8; c++) {
    uint4 u = *(const uint4*)(kp + c * 8);
    unpack2(u.x, kk[c * 8 + 0], kk[c * 8 + 1]);
    unpack2(u.y, kk[c * 8 + 2], kk[c * 8 + 3]);
    unpack2(u.z, kk[c * 8 + 4], kk[c * 8 + 5]);
    unpack2(u.w, kk[c * 8 + 6], kk[c * 8 + 7]);
  }
  if (n > 0) {
    const float* rp = rope + (size_t)(n - 1) * 128;
#pragma unroll
    for (int c = 0; c < 8; c++) {
      float sn[8], cs[8];
      *(float4*)&sn[0] = *(const float4*)(rp + c * 8);
      *(float4*)&sn[4] = *(const float4*)(rp + c * 8 + 4);
      *(float4*)&cs[0] = *(const float4*)(rp + 64 + c * 8);
      *(float4*)&cs[4] = *(const float4*)(rp + 64 + c * 8 + 4);
#pragma unroll
      for (int i = 0; i < 4; i++) {
        float e = kk[c * 8 + 2 * i], o = kk[c * 8 + 2 * i + 1];
        kk[c * 8 + 2 * i] = e * cs[2 * i] - o * sn[2 * i];
        kk[c * 8 + 2 * i + 1] = o * cs[2 * i + 1] + e * sn[2 * i + 1];
      }
    }
  }
  float mx = kk[0];
#pragma unroll
  for (int i = 1; i < 64; i++) mx = fmaxf(mx, kk[i]);
  float s = 0.f;
#pragma unroll
  for (int i = 0; i < 64; i++) { float e = __expf(kk[i] - mx); kk[i] = e; s += e; }
  const float inv = 1.f / s;

  // ---- transpose-write phi (bf16) and v into [row][256] swizzled LDS ----
  const int tc = t >> 3, tl = t & 7;  // logical chunk (0..31) / pos in chunk
#pragma unroll
  for (int d = 0; d < 64; d++)
    sphiT[d * 256 + ((tc ^ (d & 7)) * 8) + tl] = f2b(kk[d] * inv);
  {
    const unsigned short* vp = qkv + rowb + 1536 + h * 64;
    unsigned short vraw[64];
#pragma unroll
    for (int c = 0; c < 8; c++)
      *(uint4*)&vraw[c * 8] = *(const uint4*)(vp + c * 8);
#pragma unroll
    for (int e = 0; e < 64; e++)
      svT[e * 256 + ((tc ^ (e & 7)) * 8) + tl] = vraw[e];
  }
  __syncthreads();

  // ---- MFMA: wave w owns d-rows [w*16, w*16+16), full K=256 ----
  const int lane = t & 63, w = t >> 6;
  const int mr = lane & 15, kq = lane >> 4;
  floatx4 acc[4] = {};   // e-blocks 0..3
  floatx4 accs = {};     // ksum (ones B-frag)
  short8 ones;
#pragma unroll
  for (int i = 0; i < 8; i++) ones[i] = (short)0x3F80;  // bf16 1.0
  const int d = w * 16 + mr;
#pragma unroll
  for (int ks = 0; ks < 8; ks++) {
    const int clog = ks * 4 + kq;  // chunk 0..31
    short8 af = *(const short8*)&sphiT[d * 256 + ((clog ^ (d & 7)) * 8)];
#pragma unroll
    for (int j = 0; j < 4; j++) {
      const int e = j * 16 + mr;
      short8 bf_ = *(const short8*)&svT[e * 256 + ((clog ^ (e & 7)) * 8)];
      acc[j] = __builtin_amdgcn_mfma_f32_16x16x32_bf16(af, bf_, acc[j], 0, 0, 0);
    }
    accs = __builtin_amdgcn_mfma_f32_16x16x32_bf16(af, ones, accs, 0, 0, 0);
  }

  // ---- write partials: D row = d' = w*16 + (lane>>4)*4 + r, col = e ----
  float* o = kvP + ((size_t)bh * SPLIT_A + sp) * 4160;
  const int dr0 = w * 16 + (lane >> 4) * 4;
  const int nc = lane & 15;
#pragma unroll
  for (int j = 0; j < 4; j++) {
    const int e = j * 16 + nc;
    float4 s4;
    s4.x = acc[j][0]; s4.y = acc[j][1]; s4.z = acc[j][2]; s4.w = acc[j][3];
    *(float4*)&o[e * 64 + dr0] = s4;
  }
  if (nc == 0) {
    float4 s4;
    s4.x = accs[0]; s4.y = accs[1]; s4.z = accs[2]; s4.w = accs[3];
    *(float4*)&o[4096 + dr0] = s4;
  }
}

// ---------------------------------------------------------------------------
__global__ __launch_bounds__(256) void reduce_kv(
    const float* __restrict__ kvP, float* __restrict__ kvG) {
  const int i = blockIdx.x * 256 + threadIdx.x;
  if (i >= 96 * 4160) return;
  const int bh = i / 4160, r = i - bh * 4160;
  const float* p = kvP + (size_t)bh * SPLIT_A * 4160 + r;
  float s = 0.f;
#pragma unroll
  for (int sp = 0; sp < SPLIT_A; sp++) s += p[(size_t)sp * 4160];
  kvG[i] = s;
}

// ---------------------------------------------------------------------------
// pass_b (MFMA): phi/kv bf16 in swizzled LDS; 32 MFMA/wave. (R6-verified)
// ---------------------------------------------------------------------------
__global__ __launch_bounds__(256) void pass_b(
    const unsigned short* __restrict__ qkv, const float* __restrict__ rope,
    const float* __restrict__ kvG, unsigned short* __restrict__ attn) {
  __shared__ __align__(16) unsigned short sp_[256 * 64];
  __shared__ __align__(16) unsigned short skv[64 * 64];
  __shared__ float szi[256];
  __shared__ float sks[64];
  const int bh = blockIdx.x, b = bh / 12, h = bh % 12;
  const int t = threadIdx.x;
  const float* kvb = kvG + (size_t)bh * 4160;

  {
    const int e = t >> 2, q = t & 3;
    const float* src = kvb + e * 64 + q * 16;
    unsigned short tmp[16];
#pragma unroll
    for (int i = 0; i < 16; i++) tmp[i] = f2b(src[i]);
    *(uint4*)&skv[e * 64 + (((q * 2) ^ (e & 7)) * 8)] = *(uint4*)&tmp[0];
    *(uint4*)&skv[e * 64 + (((q * 2 + 1) ^ (e & 7)) * 8)] = *(uint4*)&tmp[8];
  }
  if (t < 64) sks[t] = kvb[4096 + t];
  __syncthreads();

  const int n = blockIdx.y * 256 + t;
  const size_t rowb = (size_t)(b * 4096 + n) * 2304;
  const unsigned short* qp = qkv + rowb + h * 64;
  float ph[64];
#pragma unroll
  for (int c = 0; c < 8; c++) {
    uint4 u = *(const uint4*)(qp + c * 8);
    unpack2(u.x, ph[c * 8 + 0], ph[c * 8 + 1]);
    unpack2(u.y, ph[c * 8 + 2], ph[c * 8 + 3]);
    unpack2(u.z, ph[c * 8 + 4], ph[c * 8 + 5]);
    unpack2(u.w, ph[c * 8 + 6], ph[c * 8 + 7]);
  }
  if (n > 0) {
    const float* rp = rope + (size_t)(n - 1) * 128;
#pragma unroll
    for (int c = 0; c < 8; c++) {
      float sn[8], cs[8];
      *(float4*)&sn[0] = *(const float4*)(rp + c * 8);
      *(float4*)&sn[4] = *(const float4*)(rp + c * 8 + 4);
      *(float4*)&cs[0] = *(const float4*)(rp + 64 + c * 8);
      *(float4*)&cs[4] = *(const float4*)(rp + 64 + c * 8 + 4);
#pragma unroll
      for (int i = 0; i < 4; i++) {
        float e = ph[c * 8 + 2 * i], o = ph[c * 8 + 2 * i + 1];
        ph[c * 8 + 2 * i] = e * cs[2 * i] - o * sn[2 * i];
        ph[c * 8 + 2 * i + 1] = o * cs[2 * i + 1] + e * sn[2 * i + 1];
      }
    }
  }
  float mx = ph[0];
#pragma unroll
  for (int i = 1; i < 64; i++) mx = fmaxf(mx, ph[i]);
  float s = 0.f;
#pragma unroll
  for (int i = 0; i < 64; i++) { float e = __expf(ph[i] - mx); ph[i] = e; s += e; }
  const float inv = 1.f / s;
  float z = 0.f;
#pragma unroll
  for (int i = 0; i < 64; i++) { ph[i] *= inv; z += ph[i] * sks[i]; }
  szi[t] = 1.f / (z + 1e-5f);

#pragma unroll
  for (int sl = 0; sl < 8; sl += 2) {
    unsigned short tmp[16];
#pragma unroll
    for (int i = 0; i < 16; i++) tmp[i] = f2b(ph[sl * 8 + i]);
    *(uint4*)&sp_[t * 64 + ((sl ^ (t & 7)) * 8)] = *(uint4*)&tmp[0];
    *(uint4*)&sp_[t * 64 + (((sl + 1) ^ (t & 7)) * 8)] = *(uint4*)&tmp[8];
  }
  __syncthreads();

  const int lane = t & 63, wv = t >> 6;
  const int fr = lane & 15, fq = lane >> 4;
  floatx4 acc[4][4] = {};
#pragma unroll
  for (int kk = 0; kk < 2; kk++) {
    short8 kvf[4], pf[4];
#pragma unroll
    for (int j = 0; j < 4; j++) {
      const int e = j * 16 + fr;
      kvf[j] = *(const short8*)&skv[e * 64 + (((kk * 4 + fq) ^ (e & 7)) * 8)];
    }
#pragma unroll
    for (int i = 0; i < 4; i++) {
      const int tok = wv * 64 + i * 16 + fr;
      pf[i] = *(const short8*)&sp_[tok * 64 + (((kk * 4 + fq) ^ (tok & 7)) * 8)];
    }
#pragma unroll
    for (int i = 0; i < 4; i++)
#pragma unroll
      for (int j = 0; j < 4; j++)
        acc[i][j] = __builtin_amdgcn_mfma_f32_16x16x32_bf16(kvf[j], pf[i], acc[i][j], 0, 0, 0);
  }

#pragma unroll
  for (int i = 0; i < 4; i++) {
    const int tokl = wv * 64 + i * 16 + fr;
    const float zi = szi[tokl];
    unsigned short* orow =
        attn + (size_t)(b * 4096 + blockIdx.y * 256 + tokl) * 768 + h * 64;
#pragma unroll
    for (int j = 0; j < 4; j++) {
      const int e0 = j * 16 + fq * 4;
      unsigned short pk[4] = {f2b(acc[i][j][0] * zi), f2b(acc[i][j][1] * zi),
                              f2b(acc[i][j][2] * zi), f2b(acc[i][j][3] * zi)};
      *(uint2*)(orow + e0) = *(const uint2*)pk;
    }
  }
}

// ---------------------------------------------------------------------------
__global__ __launch_bounds__(256) void ln_kernel(
    unsigned short* __restrict__ buf, const float* __restrict__ g,
    const float* __restrict__ be) {
  const int row = blockIdx.x;
  const int t = threadIdx.x;
  unsigned short* p = buf + (size_t)row * 768;
  const float x0 = b2f(p[t]), x1 = b2f(p[t + 256]), x2 = b2f(p[t + 512]);
  float s = x0 + x1 + x2;
  float ss = x0 * x0 + x1 * x1 + x2 * x2;
#pragma unroll
  for (int m = 1; m < 64; m <<= 1) { s += __shfl_xor(s, m); ss += __shfl_xor(ss, m); }
  __shared__ float red[8];
  const int wave = t >> 6, lane = t & 63;
  if (lane == 0) { red[wave] = s; red[4 + wave] = ss; }
  __syncthreads();
  s = red[0] + red[1] + red[2] + red[3];
  ss = red[4] + red[5] + red[6] + red[7];
  const float mean = s * (1.f / 768.f);
  const float var = ss * (1.f / 768.f) - mean * mean;
  const float rsq = rsqrtf(var + 1e-5f);
  p[t] = f2b((x0 - mean) * rsq * g[t] + be[t]);
  p[t + 256] = f2b((x1 - mean) * rsq * g[t + 256] + be[t + 256]);
  p[t + 512] = f2b((x2 - mean) * rsq * g[t + 512] + be[t + 512]);
}

// ---------------------------------------------------------------------------
extern "C" void kernel_launch(void* const* d_in, const int* in_sizes, int n_in,
                              void* d_out, int out_size, void* d_ws, size_t ws_size,
                              hipStream_t stream) {
  (void)in_sizes; (void)n_in; (void)out_size; (void)ws_size;
  const float* x      = (const float*)d_in[0];
  const float* rope   = (const float*)d_in[1];
  const float* qkv_w  = (const float*)d_in[2];
  const float* q_bias = (const float*)d_in[3];
  const float* v_bias = (const float*)d_in[4];
  const float* norm_g = (const float*)d_in[5];
  const float* norm_b = (const float*)d_in[6];
  const float* proj_w = (const float*)d_in[7];
  const float* proj_b = (const float*)d_in[8];

  char* ws = (char*)d_ws;
  unsigned short* qkv  = (unsigned short*)ws;                // 150,994,944 B
  unsigned short* attn = (unsigned short*)(ws + 150994944);  //  50,331,648 B
  unsigned short* xbf  = attn;  // aliased: x_bf16 dead before attn is written
  float* kvP   = (float*)(ws + 150994944);  // aliased: partials dead before attn
  float* kvG   = (float*)(ws + 201326592);                   //   1,597,440 B
  float* qkvb  = (float*)(ws + 202924032);
  float* projb = (float*)(ws + 202933248);
  unsigned short* wbf  = (unsigned short*)(ws + 202936320);  //   3,538,944 B
  unsigned short* pwbf = (unsigned short*)(ws + 206475264);  //   1,179,648 B

  hipFuncSetAttribute(reinterpret_cast<const void*>(&gemm256),
                      hipFuncAttributeMaxDynamicSharedMemorySize, 131072);

  f32_to_bf16<<<dim3(12288), dim3(256), 0, stream>>>(x, xbf, 25165824);
  prep<<<dim3(1161), dim3(256), 0, stream>>>(qkv_w, proj_w, q_bias, v_bias,
                                             proj_b, wbf, pwbf, qkvb, projb);
  // qkv = x @ qkv_w^T + qkv_bias (M=32768, K=768, Nout=2304), bf16 out
  gemm256<<<dim3(1152), dim3(512), 131072, stream>>>(xbf, wbf, qkvb, qkv,
                                                     768, 2304, 9, 12);
  // NOTE: xbf (== kvP region) is dead from here on.
  pass_a<<<dim3(96, SPLIT_A), dim3(256), 0, stream>>>(qkv, rope, kvP);
  reduce_kv<<<dim3(1560), dim3(256), 0, stream>>>(kvP, kvG);
  pass_b<<<dim3(96, 16), dim3(256), 0, stream>>>(qkv, rope, kvG, attn);
  ln_kernel<<<dim3(32768), dim3(256), 0, stream>>>(attn, norm_g, norm_b);
  // out = ln @ proj_w^T + proj_b (M=32768, K=768, Nout=768) -> d_out fp32
  gemm_bt<0><<<dim3(1536), dim3(256), 0, stream>>>(attn, pwbf, projb, d_out,
                                                   32768, 768, 768, 6);
}